// Round 1
// baseline (326.078 us; speedup 1.0000x reference)
//
#include <hip/hip_runtime.h>
#include <stdint.h>

#define NB 16
#define NA 8400
#define NCH 84
#define NCLS 80
#define CANDN 2048
#define MAXDET 300
#define SORT_N 16384

typedef unsigned long long u64;

// ---------------- workspace layout (bytes) ----------------
// keys : 16*8400*8  = 1075200
// cls  : 16*8400*4  =  537600
// tidx : 16*2048*4  =  131072
// tsc  : 16*2048*4  =  131072
// cand : 16*2048*24 =  786432
// nmsb : 16*2048*16 =  524288
// area : 16*2048*4  =  131072
// vmask: 16*32*8    =    4096
// M    : 16*2048*32*8 = 8388608
static const size_t OFF_KEYS = 0;
static const size_t OFF_CLS  = 1075200;
static const size_t OFF_TIDX = 1612800;
static const size_t OFF_TSC  = 1743872;
static const size_t OFF_CAND = 1874944;
static const size_t OFF_NMS  = 2661376;
static const size_t OFF_AREA = 3185664;
static const size_t OFF_VAL  = 3316736;
static const size_t OFF_M    = 3320832;
// total ~11.7 MB

// ---------- kernel 1: per-anchor class max + argmax, build sort key ----------
__global__ __launch_bounds__(256) void score_kernel(const float* __restrict__ pred,
                                                    u64* __restrict__ keys,
                                                    int* __restrict__ cls) {
  int a = blockIdx.x * 256 + threadIdx.x;
  int b = blockIdx.y;
  if (a >= NA) return;
  const float* p = pred + (size_t)b * (NCH * NA) + 4 * NA + a;
  float best = p[0];
  int bc = 0;
#pragma unroll 8
  for (int c = 1; c < NCLS; ++c) {
    float v = p[(size_t)c * NA];
    if (v > best) { best = v; bc = c; }  // strict > : first-index argmax
  }
  // descending score, ascending index on ties, via ascending uint64 sort
  keys[b * NA + a] = (((u64)(~__float_as_uint(best))) << 32) | (unsigned int)a;
  cls[b * NA + a] = bc;
}

// ---------- kernel 2: per-image bitonic sort of 16384 padded keys ----------
__global__ __launch_bounds__(1024) void sort_kernel(const u64* __restrict__ keys,
                                                    int* __restrict__ tidx,
                                                    float* __restrict__ tsc) {
  __shared__ u64 sk[SORT_N];  // 128 KiB LDS
  int b = blockIdx.x;
  int tid = threadIdx.x;
  for (int i = tid; i < SORT_N; i += 1024)
    sk[i] = (i < NA) ? keys[b * NA + i] : ~0ULL;
  __syncthreads();
  for (int kk = 2; kk <= SORT_N; kk <<= 1) {
    for (int j = kk >> 1; j > 0; j >>= 1) {
      for (int p = tid; p < SORT_N / 2; p += 1024) {
        int low = p & (j - 1);
        int i = ((p ^ low) << 1) | low;
        int l = i | j;
        u64 a = sk[i];
        u64 c = sk[l];
        bool asc = (i & kk) == 0;
        if ((a > c) == asc) { sk[i] = c; sk[l] = a; }
      }
      __syncthreads();
    }
  }
  for (int t = tid; t < CANDN; t += 1024) {
    u64 key = sk[t];
    tidx[b * CANDN + t] = (int)(unsigned int)(key & 0xFFFFFFFFu);
    tsc[b * CANDN + t] = __uint_as_float(~(unsigned int)(key >> 32));
  }
}

// ---------- kernel 3: gather box, xyxy, nms-box, area, valid mask ----------
__global__ __launch_bounds__(256) void prep_kernel(const float* __restrict__ pred,
                                                   const int* __restrict__ tidx,
                                                   const float* __restrict__ tsc,
                                                   const int* __restrict__ cls,
                                                   const int* __restrict__ imgsz,
                                                   float* __restrict__ cand,
                                                   float4* __restrict__ nmsb,
                                                   float* __restrict__ area,
                                                   u64* __restrict__ vmask) {
  int k = blockIdx.x * 256 + threadIdx.x;
  int b = blockIdx.y;
  int o = b * CANDN + k;
  int idx = tidx[o];
  float score = tsc[o];
  const float* pb = pred + (size_t)b * (NCH * NA);
  float x = pb[0 * NA + idx];
  float y = pb[1 * NA + idx];
  float w = pb[2 * NA + idx];
  float h = pb[3 * NA + idx];
  float hw = __fmul_rn(w, 0.5f);
  float hh = __fmul_rn(h, 0.5f);
  float x1 = __fsub_rn(x, hw);
  float y1 = __fsub_rn(y, hh);
  float x2 = __fadd_rn(x, hw);
  float y2 = __fadd_rn(y, hh);
  float clsf = (float)cls[b * NA + idx];
  float inv = (float)(1.0 / (double)imgsz[0]);
  float nx1 = __fadd_rn(__fmul_rn(x1, inv), clsf);
  float ny1 = __fadd_rn(__fmul_rn(y1, inv), clsf);
  float nx2 = __fadd_rn(__fmul_rn(x2, inv), clsf);
  float ny2 = __fadd_rn(__fmul_rn(y2, inv), clsf);
  float ar = __fmul_rn(__fsub_rn(nx2, nx1), __fsub_rn(ny2, ny1));
  bool valid = score > 0.25f;
  cand[(size_t)o * 6 + 0] = x1;
  cand[(size_t)o * 6 + 1] = y1;
  cand[(size_t)o * 6 + 2] = x2;
  cand[(size_t)o * 6 + 3] = y2;
  cand[(size_t)o * 6 + 4] = score;
  cand[(size_t)o * 6 + 5] = clsf;
  nmsb[o] = make_float4(nx1, ny1, nx2, ny2);
  area[o] = ar;
  u64 bal = __ballot(valid);
  if ((threadIdx.x & 63) == 0) vmask[b * 32 + (k >> 6)] = bal;
}

// ---------- kernel 4: suppression bit-matrix M[i][word] ----------
__global__ __launch_bounds__(256) void iou_kernel(const float4* __restrict__ nmsb,
                                                  const float* __restrict__ area,
                                                  u64* __restrict__ M) {
  int i = blockIdx.x;
  int b = blockIdx.y;
  int wv = threadIdx.x >> 6;
  int lane = threadIdx.x & 63;
  int ob = b * CANDN;
  float4 bi = nmsb[ob + i];
  float ai = area[ob + i];
#pragma unroll
  for (int it = 0; it < 8; ++it) {
    int w = wv + it * 4;  // words 0..31
    int j = (w << 6) + lane;
    float4 bj = nmsb[ob + j];
    float aj = area[ob + j];
    float ix1 = fmaxf(bi.x, bj.x);
    float iy1 = fmaxf(bi.y, bj.y);
    float ix2 = fminf(bi.z, bj.z);
    float iy2 = fminf(bi.w, bj.w);
    float iw = fmaxf(__fsub_rn(ix2, ix1), 0.0f);
    float ih = fmaxf(__fsub_rn(iy2, iy1), 0.0f);
    float inter = __fmul_rn(iw, ih);
    float denom = __fadd_rn(__fsub_rn(__fadd_rn(ai, aj), inter), 1e-7f);
    float iou = __fdiv_rn(inter, denom);
    u64 bal = __ballot(iou > 0.45f);
    if (lane == 0) M[(((size_t)(ob + i)) << 5) + w] = bal;
  }
}

// ---------- kernel 5: sequential greedy scan, one wave per image ----------
__global__ __launch_bounds__(64) void scan_kernel(const u64* __restrict__ M,
                                                  const u64* __restrict__ vmaskg,
                                                  const float* __restrict__ cand,
                                                  float* __restrict__ out) {
  int b = blockIdx.x;
  int lane = threadIdx.x;
  u64 vmask = (lane < 32) ? vmaskg[b * 32 + lane] : 0ULL;
  u64 remv = 0ULL;
  const u64* Mb = M + (((size_t)b * CANDN) << 5);
  u64 buf[8];
#pragma unroll
  for (int d = 0; d < 8; ++d)
    buf[d] = (lane < 32) ? Mb[((size_t)d << 5) + lane] : 0ULL;
  int cnt = 0;
  for (int base = 0; base < CANDN; base += 8) {
#pragma unroll
    for (int d = 0; d < 8; ++d) {
      int i = base + d;
      u64 row = buf[d];
      int nx = i + 8;
      buf[d] = (lane < 32 && nx < CANDN) ? Mb[((size_t)nx << 5) + lane] : 0ULL;
      int w = i >> 6;
      int bp = i & 63;
      u64 sv = __shfl(vmask, w);
      u64 sr = __shfl(remv, w);
      bool keep = (((sv >> bp) & 1ULL) != 0ULL) && (((sr >> bp) & 1ULL) == 0ULL);
      if (keep) {
        remv |= row;
        if (cnt < MAXDET) {
          if (lane < 6)
            out[((size_t)(b * MAXDET + cnt)) * 6 + lane] =
                cand[((size_t)(b * CANDN + i)) * 6 + lane];
        }
        cnt++;
      }
    }
    if (cnt >= MAXDET) break;
  }
  // zero-fill remaining rows (out is poisoned, must be written every call)
  for (int x = cnt * 6 + lane; x < MAXDET * 6; x += 64)
    out[(size_t)b * (MAXDET * 6) + x] = 0.0f;
}

extern "C" void kernel_launch(void* const* d_in, const int* in_sizes, int n_in,
                              void* d_out, int out_size, void* d_ws, size_t ws_size,
                              hipStream_t stream) {
  (void)in_sizes; (void)n_in; (void)out_size; (void)ws_size;
  const float* pred = (const float*)d_in[0];
  const int* imgsz = (const int*)d_in[1];
  char* ws = (char*)d_ws;
  u64* keys = (u64*)(ws + OFF_KEYS);
  int* cls = (int*)(ws + OFF_CLS);
  int* tidx = (int*)(ws + OFF_TIDX);
  float* tsc = (float*)(ws + OFF_TSC);
  float* cand = (float*)(ws + OFF_CAND);
  float4* nmsb = (float4*)(ws + OFF_NMS);
  float* area = (float*)(ws + OFF_AREA);
  u64* vmask = (u64*)(ws + OFF_VAL);
  u64* M = (u64*)(ws + OFF_M);
  float* out = (float*)d_out;

  score_kernel<<<dim3((NA + 255) / 256, NB), 256, 0, stream>>>(pred, keys, cls);
  sort_kernel<<<NB, 1024, 0, stream>>>(keys, tidx, tsc);
  prep_kernel<<<dim3(CANDN / 256, NB), 256, 0, stream>>>(pred, tidx, tsc, cls, imgsz,
                                                         cand, nmsb, area, vmask);
  iou_kernel<<<dim3(CANDN, NB), 256, 0, stream>>>(nmsb, area, M);
  scan_kernel<<<NB, 64, 0, stream>>>(M, vmask, cand, out);
}

// Round 2
// 226.663 us; speedup vs baseline: 1.4386x; 1.4386x over previous
//
#include <hip/hip_runtime.h>
#include <stdint.h>

#define NB 16
#define NA 8400
#define NA_PAD 9216
#define NCH 84
#define NCLS 80
#define CANDN 2048
#define MAXDET 300

typedef unsigned long long u64;

// ---------------- workspace layout (bytes) ----------------
static const size_t OFF_KEYS = 0;
static const size_t OFF_CLS  = 1075200;
static const size_t OFF_TIDX = 1612800;
static const size_t OFF_TSC  = 1743872;
static const size_t OFF_CAND = 1874944;
static const size_t OFF_NMS  = 2661376;
static const size_t OFF_AREA = 3185664;
static const size_t OFF_VAL  = 3316736;
static const size_t OFF_M    = 3320832;
// total ~11.7 MB

// ---------- kernel 1: per-anchor class max + argmax, build sort key ----------
__global__ __launch_bounds__(256) void score_kernel(const float* __restrict__ pred,
                                                    u64* __restrict__ keys,
                                                    int* __restrict__ cls) {
  int a = blockIdx.x * 256 + threadIdx.x;
  int b = blockIdx.y;
  if (a >= NA) return;
  const float* p = pred + (size_t)b * (NCH * NA) + 4 * NA + a;
  float best = p[0];
  int bc = 0;
#pragma unroll 8
  for (int c = 1; c < NCLS; ++c) {
    float v = p[(size_t)c * NA];
    if (v > best) { best = v; bc = c; }  // strict > : first-index argmax
  }
  // descending score, ascending index on ties, via ascending uint64 sort
  keys[b * NA + a] = (((u64)(~__float_as_uint(best))) << 32) | (unsigned int)a;
  cls[b * NA + a] = bc;
}

// ---------- kernel 2: radix-select top-2048 + bitonic sort of the 2048 ----------
__global__ __launch_bounds__(1024) void select_kernel(const u64* __restrict__ keys,
                                                      int* __restrict__ tidx,
                                                      float* __restrict__ tsc) {
  __shared__ u64 skeys[NA];       // 67200 B
  __shared__ u64 sortbuf[CANDN];  // 16384 B
  __shared__ int hist[256];
  __shared__ int cum[256];
  __shared__ u64 sh_prefix;
  __shared__ int sh_k;
  __shared__ int sh_cnt;

  int b = blockIdx.x;
  int tid = threadIdx.x;
  int lane = tid & 63;

  for (int i = tid; i < NA; i += 1024) skeys[i] = keys[b * NA + i];
  if (tid == 0) { sh_prefix = 0; sh_k = CANDN; sh_cnt = 0; }
  __syncthreads();

  u64 prefix = 0;
  int k = CANDN;
  for (int shift = 56; shift >= 0; shift -= 8) {
    if (tid < 256) hist[tid] = 0;
    __syncthreads();
    u64 pmask = (shift == 56) ? 0ULL : (~0ULL << (shift + 8));
    for (int i = tid; i < NA_PAD; i += 1024) {
      bool act = false;
      int d = 0;
      if (i < NA) {
        u64 key = skeys[i];
        act = (key & pmask) == prefix;
        d = (int)((key >> shift) & 255);
      }
      // wave-aggregate same-digit counts (scores cluster -> few hot bins)
      u64 m = __ballot(act);
      if (m) {
#pragma unroll
        for (int bit = 0; bit < 8; ++bit) {
          u64 bb = __ballot((d >> bit) & 1);
          m &= ((d >> bit) & 1) ? bb : ~bb;
        }
        if (act && (m & ((1ULL << lane) - 1)) == 0ULL)
          atomicAdd(&hist[d], (int)__popcll(m));
      }
    }
    __syncthreads();
    // inclusive scan of 256 bins by wave 0 (4 bins/lane, shfl scan, no barriers)
    if (tid < 64) {
      int v0 = hist[tid * 4 + 0], v1 = hist[tid * 4 + 1];
      int v2 = hist[tid * 4 + 2], v3 = hist[tid * 4 + 3];
      int s0 = v0, s1 = s0 + v1, s2 = s1 + v2, s3 = s2 + v3;
      int tot = s3;
      for (int off = 1; off < 64; off <<= 1) {
        int t = __shfl_up(tot, off, 64);
        if (tid >= off) tot += t;
      }
      int base = tot - s3;  // exclusive prefix of this lane's 4-bin group
      cum[tid * 4 + 0] = base + s0;
      cum[tid * 4 + 1] = base + s1;
      cum[tid * 4 + 2] = base + s2;
      cum[tid * 4 + 3] = base + s3;
    }
    __syncthreads();
    if (tid < 256) {
      int c = cum[tid];
      int cprev = (tid == 0) ? 0 : cum[tid - 1];
      if (c >= k && cprev < k) {  // exactly one digit satisfies this
        sh_prefix = prefix | ((u64)tid << shift);
        sh_k = k - cprev;
      }
    }
    __syncthreads();
    prefix = sh_prefix;
    k = sh_k;
  }

  // prefix == exact 2048th-smallest key; keys distinct -> exactly 2048 pass
  for (int i = tid; i < NA_PAD; i += 1024) {
    bool act = false;
    u64 key = 0;
    if (i < NA) { key = skeys[i]; act = key <= prefix; }
    u64 mm = __ballot(act);
    if (mm) {
      int leader = __ffsll(mm) - 1;
      int base = 0;
      if (lane == leader) base = atomicAdd(&sh_cnt, (int)__popcll(mm));
      base = __shfl(base, leader, 64);
      if (act) sortbuf[base + (int)__popcll(mm & ((1ULL << lane) - 1))] = key;
    }
  }
  __syncthreads();

  // bitonic sort 2048 keys ascending, 1024 threads = 1 comparator each
  for (int kk = 2; kk <= CANDN; kk <<= 1) {
    for (int j = kk >> 1; j > 0; j >>= 1) {
      int low = tid & (j - 1);
      int i2 = ((tid ^ low) << 1) | low;
      int l = i2 | j;
      u64 a = sortbuf[i2];
      u64 c = sortbuf[l];
      bool asc = (i2 & kk) == 0;
      if ((a > c) == asc) { sortbuf[i2] = c; sortbuf[l] = a; }
      __syncthreads();
    }
  }

  for (int t = tid; t < CANDN; t += 1024) {
    u64 key = sortbuf[t];
    tidx[b * CANDN + t] = (int)(unsigned int)(key & 0xFFFFFFFFu);
    tsc[b * CANDN + t] = __uint_as_float(~(unsigned int)(key >> 32));
  }
}

// ---------- kernel 3: gather box, xyxy, nms-box, area, valid mask ----------
__global__ __launch_bounds__(256) void prep_kernel(const float* __restrict__ pred,
                                                   const int* __restrict__ tidx,
                                                   const float* __restrict__ tsc,
                                                   const int* __restrict__ cls,
                                                   const int* __restrict__ imgsz,
                                                   float* __restrict__ cand,
                                                   float4* __restrict__ nmsb,
                                                   float* __restrict__ area,
                                                   u64* __restrict__ vmask) {
  int k = blockIdx.x * 256 + threadIdx.x;
  int b = blockIdx.y;
  int o = b * CANDN + k;
  int idx = tidx[o];
  float score = tsc[o];
  const float* pb = pred + (size_t)b * (NCH * NA);
  float x = pb[0 * NA + idx];
  float y = pb[1 * NA + idx];
  float w = pb[2 * NA + idx];
  float h = pb[3 * NA + idx];
  float hw = __fmul_rn(w, 0.5f);
  float hh = __fmul_rn(h, 0.5f);
  float x1 = __fsub_rn(x, hw);
  float y1 = __fsub_rn(y, hh);
  float x2 = __fadd_rn(x, hw);
  float y2 = __fadd_rn(y, hh);
  float clsf = (float)cls[b * NA + idx];
  float inv = (float)(1.0 / (double)imgsz[0]);
  float nx1 = __fadd_rn(__fmul_rn(x1, inv), clsf);
  float ny1 = __fadd_rn(__fmul_rn(y1, inv), clsf);
  float nx2 = __fadd_rn(__fmul_rn(x2, inv), clsf);
  float ny2 = __fadd_rn(__fmul_rn(y2, inv), clsf);
  float ar = __fmul_rn(__fsub_rn(nx2, nx1), __fsub_rn(ny2, ny1));
  bool valid = score > 0.25f;
  cand[(size_t)o * 6 + 0] = x1;
  cand[(size_t)o * 6 + 1] = y1;
  cand[(size_t)o * 6 + 2] = x2;
  cand[(size_t)o * 6 + 3] = y2;
  cand[(size_t)o * 6 + 4] = score;
  cand[(size_t)o * 6 + 5] = clsf;
  nmsb[o] = make_float4(nx1, ny1, nx2, ny2);
  area[o] = ar;
  u64 bal = __ballot(valid);
  if ((threadIdx.x & 63) == 0) vmask[b * 32 + (k >> 6)] = bal;
}

// ---------- kernel 4: suppression bit-matrix M[i][word] ----------
__global__ __launch_bounds__(256) void iou_kernel(const float4* __restrict__ nmsb,
                                                  const float* __restrict__ area,
                                                  u64* __restrict__ M) {
  int i = blockIdx.x;
  int b = blockIdx.y;
  int wv = threadIdx.x >> 6;
  int lane = threadIdx.x & 63;
  int ob = b * CANDN;
  float4 bi = nmsb[ob + i];
  float ai = area[ob + i];
#pragma unroll
  for (int it = 0; it < 8; ++it) {
    int w = wv + it * 4;  // words 0..31
    int j = (w << 6) + lane;
    float4 bj = nmsb[ob + j];
    float aj = area[ob + j];
    float ix1 = fmaxf(bi.x, bj.x);
    float iy1 = fmaxf(bi.y, bj.y);
    float ix2 = fminf(bi.z, bj.z);
    float iy2 = fminf(bi.w, bj.w);
    float iw = fmaxf(__fsub_rn(ix2, ix1), 0.0f);
    float ih = fmaxf(__fsub_rn(iy2, iy1), 0.0f);
    float inter = __fmul_rn(iw, ih);
    float denom = __fadd_rn(__fsub_rn(__fadd_rn(ai, aj), inter), 1e-7f);
    float iou = __fdiv_rn(inter, denom);
    u64 bal = __ballot(iou > 0.45f);
    if (lane == 0) M[(((size_t)(ob + i)) << 5) + w] = bal;
  }
}

// ---------- kernel 5: sequential greedy scan, one wave per image ----------
__global__ __launch_bounds__(64) void scan_kernel(const u64* __restrict__ M,
                                                  const u64* __restrict__ vmaskg,
                                                  const float* __restrict__ cand,
                                                  float* __restrict__ out) {
  int b = blockIdx.x;
  int lane = threadIdx.x;
  u64 vmask = (lane < 32) ? vmaskg[b * 32 + lane] : 0ULL;
  u64 remv = 0ULL;
  const u64* Mb = M + (((size_t)b * CANDN) << 5);
  u64 buf[8];
#pragma unroll
  for (int d = 0; d < 8; ++d)
    buf[d] = (lane < 32) ? Mb[((size_t)d << 5) + lane] : 0ULL;
  int cnt = 0;
  for (int base = 0; base < CANDN; base += 8) {
#pragma unroll
    for (int d = 0; d < 8; ++d) {
      int i = base + d;
      u64 row = buf[d];
      int nx = i + 8;
      buf[d] = (lane < 32 && nx < CANDN) ? Mb[((size_t)nx << 5) + lane] : 0ULL;
      int w = i >> 6;
      int bp = i & 63;
      u64 sv = __shfl(vmask, w);
      u64 sr = __shfl(remv, w);
      bool keep = (((sv >> bp) & 1ULL) != 0ULL) && (((sr >> bp) & 1ULL) == 0ULL);
      if (keep) {
        remv |= row;
        if (cnt < MAXDET) {
          if (lane < 6)
            out[((size_t)(b * MAXDET + cnt)) * 6 + lane] =
                cand[((size_t)(b * CANDN + i)) * 6 + lane];
        }
        cnt++;
      }
    }
    if (cnt >= MAXDET) break;
  }
  // zero-fill remaining rows (out is poisoned, must be written every call)
  for (int x = cnt * 6 + lane; x < MAXDET * 6; x += 64)
    out[(size_t)b * (MAXDET * 6) + x] = 0.0f;
}

extern "C" void kernel_launch(void* const* d_in, const int* in_sizes, int n_in,
                              void* d_out, int out_size, void* d_ws, size_t ws_size,
                              hipStream_t stream) {
  (void)in_sizes; (void)n_in; (void)out_size; (void)ws_size;
  const float* pred = (const float*)d_in[0];
  const int* imgsz = (const int*)d_in[1];
  char* ws = (char*)d_ws;
  u64* keys = (u64*)(ws + OFF_KEYS);
  int* cls = (int*)(ws + OFF_CLS);
  int* tidx = (int*)(ws + OFF_TIDX);
  float* tsc = (float*)(ws + OFF_TSC);
  float* cand = (float*)(ws + OFF_CAND);
  float4* nmsb = (float4*)(ws + OFF_NMS);
  float* area = (float*)(ws + OFF_AREA);
  u64* vmask = (u64*)(ws + OFF_VAL);
  u64* M = (u64*)(ws + OFF_M);
  float* out = (float*)d_out;

  score_kernel<<<dim3((NA + 255) / 256, NB), 256, 0, stream>>>(pred, keys, cls);
  select_kernel<<<NB, 1024, 0, stream>>>(keys, tidx, tsc);
  prep_kernel<<<dim3(CANDN / 256, NB), 256, 0, stream>>>(pred, tidx, tsc, cls, imgsz,
                                                         cand, nmsb, area, vmask);
  iou_kernel<<<dim3(CANDN, NB), 256, 0, stream>>>(nmsb, area, M);
  scan_kernel<<<NB, 64, 0, stream>>>(M, vmask, cand, out);
}